// Round 14
// baseline (425.517 us; speedup 1.0000x reference)
//
#include <hip/hip_runtime.h>

typedef __attribute__((ext_vector_type(8))) short short8;
typedef __attribute__((ext_vector_type(4))) float f32x4;
typedef unsigned short u16;
typedef unsigned int u32;

#define DEVI __device__ __forceinline__

// round-to-nearest-even f32 -> bf16 bits
DEVI u16 f2bf(float f) {
    union { float f; u32 u; } v; v.f = f;
    u32 r = v.u + 0x7FFFu + ((v.u >> 16) & 1u);
    return (u16)(r >> 16);
}

// ---------------- merged f32 -> bf16 convert for 3 arrays ----------------
__global__ void cvt3_kernel(const float* __restrict__ a, u16* __restrict__ oa, int na4,
                            const float* __restrict__ b, u16* __restrict__ ob, int nb4,
                            const float* __restrict__ c, u16* __restrict__ oc, int nc4) {
    int total = na4 + nb4 + nc4;
    int stride = gridDim.x * blockDim.x;
    for (int i = blockIdx.x * blockDim.x + threadIdx.x; i < total; i += stride) {
        const float* in; u16* out; int j = i;
        if (j < na4) { in = a; out = oa; }
        else if ((j -= na4) < nb4) { in = b; out = ob; }
        else { j -= nb4; in = c; out = oc; }
        float4 v = reinterpret_cast<const float4*>(in)[j];
        ushort4 o;
        o.x = f2bf(v.x); o.y = f2bf(v.y); o.z = f2bf(v.z); o.w = f2bf(v.w);
        reinterpret_cast<ushort4*>(out)[j] = o;
    }
}

// ---------------- embed + pos + leaky1 -> bf16 A ----------------
__global__ __launch_bounds__(64)
void embed_leaky_kernel(const int* __restrict__ x, const float* __restrict__ emb,
                        const float* __restrict__ pos, const float* __restrict__ beta,
                        u16* __restrict__ Aout) {
    __shared__ int xs[128];
    int gtid = blockIdx.x * 64 + threadIdx.x;
    int b = gtid >> 9;      // constant per block
    int h = gtid & 511;
    for (int i = threadIdx.x; i < 128; i += 64) xs[i] = x[i * 32 + b];
    __syncthreads();
    float be = beta[h];
    float mem = 0.f;
    for (int t0 = 0; t0 < 128; t0 += 8) {
        float e[8];
#pragma unroll
        for (int j = 0; j < 8; ++j)
            e[j] = emb[(size_t)xs[t0 + j] * 512 + h] + pos[(t0 + j) * 512 + h];
#pragma unroll
        for (int j = 0; j < 8; ++j) {
            mem = be * mem + e[j];
            Aout[(size_t)((t0 + j) * 32 + b) * 512 + h] = f2bf(mem);
        }
    }
}

// ---------------- leaky over f32 input -> bf16 A ----------------
__global__ __launch_bounds__(64)
void leaky_bf16_kernel(const float* __restrict__ in, const float* __restrict__ beta,
                       u16* __restrict__ Aout) {
    int gtid = blockIdx.x * 64 + threadIdx.x;
    int b = gtid >> 9;
    int h = gtid & 511;
    float be = beta[h];
    float mem = 0.f;
    for (int t0 = 0; t0 < 128; t0 += 8) {
        float v[8];
#pragma unroll
        for (int j = 0; j < 8; ++j)
            v[j] = in[(size_t)((t0 + j) * 32 + b) * 512 + h];
#pragma unroll
        for (int j = 0; j < 8; ++j) {
            mem = be * mem + v[j];
            Aout[(size_t)((t0 + j) * 32 + b) * 512 + h] = f2bf(mem);
        }
    }
}

// ---------------- 128x128 bf16 GEMM (round-5 proven; used for fc2/fc3) ----
template<bool RELU>
__global__ __launch_bounds__(256)
void gemm_bt_128(const u16* __restrict__ A, const u16* __restrict__ B,
                 const float* __restrict__ bias, float* __restrict__ C,
                 int M, int N, int K, int tiles_n) {
    __shared__ alignas(16) char smem[32 * 132 * 4];
    u16* As = (u16*)smem;
    u16* Bs = (u16*)(smem + 8192);
    float* Ep = (float*)smem;

    const int tid = threadIdx.x;
    int bm = blockIdx.x / tiles_n;
    int bn = blockIdx.x % tiles_n;
    const int wv = tid >> 6;
    const int lane = tid & 63;
    const int wr = wv >> 1, wc = wv & 1;
    const int lrow = lane & 15;
    const int kg = lane >> 4;
    const int kgp = kg ^ ((lrow >> 1) & 3);

    f32x4 acc[4][4];
#pragma unroll
    for (int i = 0; i < 4; ++i)
#pragma unroll
        for (int j = 0; j < 4; ++j) acc[i][j] = (f32x4){0.f, 0.f, 0.f, 0.f};

    const size_t rowb = (size_t)K * 2;
    const char* Ab = (const char*)A + (size_t)(bm * 128) * rowb;
    const char* Bb = (const char*)B + (size_t)(bn * 128) * rowb;

    float bv[4];
#pragma unroll
    for (int ni = 0; ni < 4; ++ni)
        bv[ni] = bias[bn * 128 + wc * 64 + ni * 16 + lrow];

    for (int k0 = 0; k0 < K; k0 += 32) {
        int k2 = k0 << 1;
#pragma unroll
        for (int r = 0; r < 2; ++r) {
            int s = r * 256 + tid;
            int row = s >> 2;
            int k16g = (s & 3) ^ ((row >> 1) & 3);
            size_t goff = (size_t)row * rowb + k2 + k16g * 16;
            __builtin_amdgcn_global_load_lds(
                (const __attribute__((address_space(1))) void*)(Ab + goff),
                (__attribute__((address_space(3))) void*)((char*)As + s * 16), 16, 0, 0);
            __builtin_amdgcn_global_load_lds(
                (const __attribute__((address_space(1))) void*)(Bb + goff),
                (__attribute__((address_space(3))) void*)((char*)Bs + s * 16), 16, 0, 0);
        }
        __syncthreads();

        short8 a[4], b[4];
#pragma unroll
        for (int mi = 0; mi < 4; ++mi)
            a[mi] = *(const short8*)&As[(wr * 64 + mi * 16 + lrow) * 32 + kgp * 8];
#pragma unroll
        for (int ni = 0; ni < 4; ++ni)
            b[ni] = *(const short8*)&Bs[(wc * 64 + ni * 16 + lrow) * 32 + kgp * 8];
#pragma unroll
        for (int mi = 0; mi < 4; ++mi)
#pragma unroll
            for (int ni = 0; ni < 4; ++ni)
                acc[mi][ni] = __builtin_amdgcn_mfma_f32_16x16x32_bf16(a[mi], b[ni], acc[mi][ni], 0, 0, 0);
        __syncthreads();
    }

#pragma unroll
    for (int mi = 0; mi < 4; ++mi) {
#pragma unroll
        for (int ni = 0; ni < 4; ++ni) {
            int c = wc * 64 + ni * 16 + lrow;
            f32x4 v = acc[mi][ni];
#pragma unroll
            for (int j = 0; j < 4; ++j) {
                float o = v[j] + bv[ni];
                if (RELU) o = fmaxf(o, 0.f);
                Ep[(wr * 16 + kg * 4 + j) * 132 + c] = o;
            }
        }
        __syncthreads();
#pragma unroll
        for (int rr = 0; rr < 8; ++rr) {
            int rl = wv * 8 + rr;
            int grow = bm * 128 + (rl >> 4) * 64 + mi * 16 + (rl & 15);
            size_t base = (size_t)grow * N + bn * 128;
#pragma unroll
            for (int hh = 0; hh < 2; ++hh) {
                int c = hh * 64 + lane;
                C[base + c] = Ep[rl * 132 + c];
            }
        }
        if (mi < 3) __syncthreads();
    }
}

// ---- vocab 128x128 bf16 GEMM, tri-buffer counted-vmcnt, 3 blocks/CU ------
// 256 threads = 4 waves (2x2), per-wave 64x64 (acc[4][4]); LDS 48 KB static
// (3 bufs x (A 8K + B 8K)) -> 3 blocks/CU, 12 waves/CU: one block's store
// drain / prologue refill overlaps two other blocks' K-loops.
// Staging lane-linear (m104-safe) with granule-XOR source (slice ls^(row&3));
// frag reads slot kg^(lrow&3): 2 lanes/bank = free.
// Counted vmcnt(4) (stage t+1 stays in flight), vmcnt(0) only at last iter.
// Epilogue: r5-proven LDS transpose [32][132] f32, f32x4 NT stores.
__global__ __launch_bounds__(256)
void gemm_bt_v128(const u16* __restrict__ A, const u16* __restrict__ B,
                  const float* __restrict__ bias, float* __restrict__ C,
                  int M, int N, int K, int tiles_m, int tiles_n) {
    __shared__ alignas(16) char smem[3 * 16384];   // 48 KB
    float* Ep = (float*)smem;                      // [32][132] f32 (aliases bufs)

    const int tid = threadIdx.x;
    // bijective XCD-chunked remap, bn-major (bm fastest)
    int nwg = tiles_m * tiles_n;
    int q = nwg >> 3, r = nwg & 7;
    int xcd = blockIdx.x & 7, idx = blockIdx.x >> 3;
    int wg = (xcd < r ? xcd * (q + 1) : r * (q + 1) + (xcd - r) * q) + idx;
    int bn = wg / tiles_m;
    int bm = wg % tiles_m;

    const int wv = tid >> 6;
    const int lane = tid & 63;
    const int wr = wv >> 1, wc = wv & 1;
    const int lrow = lane & 15;
    const int kg = lane >> 4;
    const int kgx = kg ^ (lrow & 3);   // swizzled 16B-slice slot for frag reads

    f32x4 acc[4][4];
#pragma unroll
    for (int i = 0; i < 4; ++i)
#pragma unroll
        for (int j = 0; j < 4; ++j) acc[i][j] = (f32x4){0.f, 0.f, 0.f, 0.f};

    const size_t rowb = (size_t)K * 2;
    const char* Ab = (const char*)A + (size_t)(bm * 128) * rowb;
    const char* Bb = (const char*)B + (size_t)(bn * 128) * rowb;

    // stage K-slab kk (32 wide): 2 A + 2 B loads/thread, lane-linear LDS dst,
    // granule-XOR'd global source within each 64B line.
    auto STAGE = [&](int bufi, int kk) {
        char* dA = smem + bufi * 16384;
        char* dB = dA + 8192;
        int k2 = kk << 1;
#pragma unroll
        for (int j = 0; j < 2; ++j) {
            int s = j * 256 + tid;          // 0..511
            int row = s >> 2, ls = s & 3;
            int gsl = ls ^ (row & 3);
            __builtin_amdgcn_global_load_lds(
                (const __attribute__((address_space(1))) void*)(Ab + (size_t)row * rowb + k2 + gsl * 16),
                (__attribute__((address_space(3))) void*)(dA + s * 16), 16, 0, 0);
        }
#pragma unroll
        for (int j = 0; j < 2; ++j) {
            int s = j * 256 + tid;
            int row = s >> 2, ls = s & 3;
            int gsl = ls ^ (row & 3);
            __builtin_amdgcn_global_load_lds(
                (const __attribute__((address_space(1))) void*)(Bb + (size_t)row * rowb + k2 + gsl * 16),
                (__attribute__((address_space(3))) void*)(dB + s * 16), 16, 0, 0);
        }
    };

    auto COMPUTE = [&](int bufi) {
        const char* Ah = smem + bufi * 16384;
        const char* Bh = Ah + 8192;
        short8 a[4], b[4];
#pragma unroll
        for (int mi = 0; mi < 4; ++mi) {
            int rr = wr * 64 + mi * 16 + lrow;    // rr&3 == lrow&3
            a[mi] = *(const short8*)(Ah + rr * 64 + kgx * 16);
        }
#pragma unroll
        for (int ni = 0; ni < 4; ++ni) {
            int rr = wc * 64 + ni * 16 + lrow;
            b[ni] = *(const short8*)(Bh + rr * 64 + kgx * 16);
        }
        __builtin_amdgcn_s_setprio(1);
#pragma unroll
        for (int mi = 0; mi < 4; ++mi)
#pragma unroll
            for (int ni = 0; ni < 4; ++ni)
                acc[mi][ni] = __builtin_amdgcn_mfma_f32_16x16x32_bf16(a[mi], b[ni], acc[mi][ni], 0, 0, 0);
        __builtin_amdgcn_s_setprio(0);
    };

    const int nt = K >> 5;   // 16 at K=512
    STAGE(0, 0);
    STAGE(1, 32);

    for (int t = 0; t < nt; ++t) {
        // drain stage(t) (oldest 4); stage(t+1) stays in flight
        if (t < nt - 1) asm volatile("s_waitcnt vmcnt(4)" ::: "memory");
        else            asm volatile("s_waitcnt vmcnt(0)" ::: "memory");
        __builtin_amdgcn_s_barrier();    // also fences buf(t+2)%3 reads (iter t-1)
        __builtin_amdgcn_sched_barrier(0);
        if (t + 2 < nt) STAGE((t + 2) % 3, (t + 2) << 5);
        COMPUTE(t % 3);
    }

    // bias after loop (keeps K-loop VMEM FIFO = stages only)
    float bv[4];
#pragma unroll
    for (int ni = 0; ni < 4; ++ni) {
        int col = bn * 128 + wc * 64 + ni * 16 + lrow;
        bv[ni] = (col < N) ? bias[col] : 0.f;
    }
    __syncthreads();  // all frag reads done before Ep overwrites LDS

    // Epilogue: 4 mi-chunks of 32 rows x 128 cols via LDS, f32x4 NT stores.
#pragma unroll
    for (int mi = 0; mi < 4; ++mi) {
#pragma unroll
        for (int ni = 0; ni < 4; ++ni) {
            int c = wc * 64 + ni * 16 + lrow;
            f32x4 v = acc[mi][ni];
#pragma unroll
            for (int j = 0; j < 4; ++j)
                Ep[(wr * 16 + kg * 4 + j) * 132 + c] = v[j] + bv[ni];
        }
        __syncthreads();
        // 4 waves x 8 rows; 2 rows per instr (half-wave each), f32x4 lanes
#pragma unroll
        for (int rr2 = 0; rr2 < 4; ++rr2) {
            int rl = wv * 8 + rr2 * 2 + (lane >> 5);
            int grow = bm * 128 + (rl >> 4) * 64 + mi * 16 + (rl & 15);
            int gc0 = bn * 128 + (lane & 31) * 4;
            f32x4 v = *(const f32x4*)&Ep[rl * 132 + (lane & 31) * 4];
            if (gc0 + 3 < N) {
                __builtin_nontemporal_store(v, (f32x4*)&C[(size_t)grow * N + gc0]);
            } else {
#pragma unroll
                for (int e = 0; e < 4; ++e)
                    if (gc0 + e < N)
                        __builtin_nontemporal_store(v[e], &C[(size_t)grow * N + gc0 + e]);
            }
        }
        if (mi < 3) __syncthreads();
    }
}

extern "C" void kernel_launch(void* const* d_in, const int* in_sizes, int n_in,
                              void* d_out, int out_size, void* d_ws, size_t ws_size,
                              hipStream_t stream) {
    const int* x    = (const int*)d_in[0];
    const float* emb = (const float*)d_in[1];
    const float* pos = (const float*)d_in[2];
    const float* b1 = (const float*)d_in[3];
    const float* b2 = (const float*)d_in[4];
    const float* b3 = (const float*)d_in[5];
    const float* w2 = (const float*)d_in[6];
    const float* fb2 = (const float*)d_in[7];
    const float* w3 = (const float*)d_in[8];
    const float* fb3 = (const float*)d_in[9];
    const float* wo = (const float*)d_in[10];
    const float* fbo = (const float*)d_in[11];
    float* out = (float*)d_out;

    const int V = 50257;
    const int TN = 393;                 // 128-col tiles for vocab
    const int Vpad = TN * 128;          // 50304

    // workspace layout
    char* p = (char*)d_ws;
    u16* WO = (u16*)p;  p += (size_t)Vpad * 512 * 2;   // 51.5 MB
    u16* W2 = (u16*)p;  p += (size_t)512 * 512 * 2;
    u16* W3 = (u16*)p;  p += (size_t)512 * 512 * 2;
    u16* Abf = (u16*)p; p += (size_t)4096 * 512 * 2;   // bf16 activations [4096,512]
    float* Hb = (float*)p;                             // f32 activations [4096,512]

    // weight conversions f32 -> bf16 (merged)
    cvt3_kernel<<<dim3(2048), dim3(256), 0, stream>>>(
        wo, WO, V * 512 / 4, w2, W2, 512 * 512 / 4, w3, W3, 512 * 512 / 4);

    // embed + pos + leaky1 -> Abf
    embed_leaky_kernel<<<dim3(256), dim3(64), 0, stream>>>(x, emb, pos, b1, Abf);

    // fc2 + relu -> Hb
    gemm_bt_128<true><<<dim3(32 * 4), dim3(256), 0, stream>>>(Abf, W2, fb2, Hb, 4096, 512, 512, 4);
    // leaky2 -> Abf
    leaky_bf16_kernel<<<dim3(256), dim3(64), 0, stream>>>(Hb, b2, Abf);
    // fc3 + relu -> Hb
    gemm_bt_128<true><<<dim3(32 * 4), dim3(256), 0, stream>>>(Abf, W3, fb3, Hb, 4096, 512, 512, 4);
    // leaky3 -> Abf
    leaky_bf16_kernel<<<dim3(256), dim3(64), 0, stream>>>(Hb, b3, Abf);
    // vocab projection -> out: 128x128, tri-buffer counted vmcnt, 3 blocks/CU
    gemm_bt_v128<<<dim3(32 * TN), dim3(256), 0, stream>>>(Abf, WO, fbo, out, 4096, V, 512, 32, TN);
}

// Round 15
// 400.815 us; speedup vs baseline: 1.0616x; 1.0616x over previous
//
#include <hip/hip_runtime.h>

typedef __attribute__((ext_vector_type(8))) short short8;
typedef __attribute__((ext_vector_type(4))) float f32x4;
typedef unsigned short u16;
typedef unsigned int u32;

#define DEVI __device__ __forceinline__

// round-to-nearest-even f32 -> bf16 bits
DEVI u16 f2bf(float f) {
    union { float f; u32 u; } v; v.f = f;
    u32 r = v.u + 0x7FFFu + ((v.u >> 16) & 1u);
    return (u16)(r >> 16);
}

// ---- fused pre-kernel: [blocks 0..63] embed+pos+leaky1; [64..] cvt3 ------
// The two halves are dependency-independent; fusing overlaps the WO convert
// (memory-bound, ~26us) with the embed gather chain (latency-bound, ~18us).
__global__ __launch_bounds__(256)
void pre_kernel(const int* __restrict__ x, const float* __restrict__ emb,
                const float* __restrict__ pos, const float* __restrict__ beta,
                u16* __restrict__ Aout,
                const float* __restrict__ wo, u16* __restrict__ WO, int nwo4,
                const float* __restrict__ w2, u16* __restrict__ W2, int nw24,
                const float* __restrict__ w3, u16* __restrict__ W3, int nw34) {
    if (blockIdx.x < 64) {
        // embed + pos + leaky1 (b constant per 256-thread block)
        __shared__ int xs[128];
        int gtid = blockIdx.x * 256 + threadIdx.x;
        int b = gtid >> 9;
        int h = gtid & 511;
        for (int i = threadIdx.x; i < 128; i += 256) xs[i] = x[i * 32 + b];
        __syncthreads();
        float be = beta[h];
        float mem = 0.f;
        for (int t0 = 0; t0 < 128; t0 += 8) {
            float e[8];
#pragma unroll
            for (int j = 0; j < 8; ++j)
                e[j] = emb[(size_t)xs[t0 + j] * 512 + h] + pos[(t0 + j) * 512 + h];
#pragma unroll
            for (int j = 0; j < 8; ++j) {
                mem = be * mem + e[j];
                Aout[(size_t)((t0 + j) * 32 + b) * 512 + h] = f2bf(mem);
            }
        }
    } else {
        // grid-stride f32->bf16 convert over WO | W2 | W3
        int total = nwo4 + nw24 + nw34;
        int nb = gridDim.x - 64;
        int stride = nb * 256;
        for (int i = (blockIdx.x - 64) * 256 + threadIdx.x; i < total; i += stride) {
            const float* in; u16* out; int j = i;
            if (j < nwo4) { in = wo; out = WO; }
            else if ((j -= nwo4) < nw24) { in = w2; out = W2; }
            else { j -= nw24; in = w3; out = W3; }
            float4 v = reinterpret_cast<const float4*>(in)[j];
            ushort4 o;
            o.x = f2bf(v.x); o.y = f2bf(v.y); o.z = f2bf(v.z); o.w = f2bf(v.w);
            reinterpret_cast<ushort4*>(out)[j] = o;
        }
    }
}

// ---------------- leaky over f32 input -> bf16 A ----------------
__global__ __launch_bounds__(64)
void leaky_bf16_kernel(const float* __restrict__ in, const float* __restrict__ beta,
                       u16* __restrict__ Aout) {
    int gtid = blockIdx.x * 64 + threadIdx.x;
    int b = gtid >> 9;
    int h = gtid & 511;
    float be = beta[h];
    float mem = 0.f;
    for (int t0 = 0; t0 < 128; t0 += 8) {
        float v[8];
#pragma unroll
        for (int j = 0; j < 8; ++j)
            v[j] = in[(size_t)((t0 + j) * 32 + b) * 512 + h];
#pragma unroll
        for (int j = 0; j < 8; ++j) {
            mem = be * mem + v[j];
            Aout[(size_t)((t0 + j) * 32 + b) * 512 + h] = f2bf(mem);
        }
    }
}

// ---------------- 128x128 bf16 GEMM (round-5 proven; used for fc2/fc3) ----
template<bool RELU>
__global__ __launch_bounds__(256)
void gemm_bt_128(const u16* __restrict__ A, const u16* __restrict__ B,
                 const float* __restrict__ bias, float* __restrict__ C,
                 int M, int N, int K, int tiles_n) {
    __shared__ alignas(16) char smem[32 * 132 * 4];
    u16* As = (u16*)smem;
    u16* Bs = (u16*)(smem + 8192);
    float* Ep = (float*)smem;

    const int tid = threadIdx.x;
    int bm = blockIdx.x / tiles_n;
    int bn = blockIdx.x % tiles_n;
    const int wv = tid >> 6;
    const int lane = tid & 63;
    const int wr = wv >> 1, wc = wv & 1;
    const int lrow = lane & 15;
    const int kg = lane >> 4;
    const int kgp = kg ^ ((lrow >> 1) & 3);

    f32x4 acc[4][4];
#pragma unroll
    for (int i = 0; i < 4; ++i)
#pragma unroll
        for (int j = 0; j < 4; ++j) acc[i][j] = (f32x4){0.f, 0.f, 0.f, 0.f};

    const size_t rowb = (size_t)K * 2;
    const char* Ab = (const char*)A + (size_t)(bm * 128) * rowb;
    const char* Bb = (const char*)B + (size_t)(bn * 128) * rowb;

    float bv[4];
#pragma unroll
    for (int ni = 0; ni < 4; ++ni)
        bv[ni] = bias[bn * 128 + wc * 64 + ni * 16 + lrow];

    for (int k0 = 0; k0 < K; k0 += 32) {
        int k2 = k0 << 1;
#pragma unroll
        for (int r = 0; r < 2; ++r) {
            int s = r * 256 + tid;
            int row = s >> 2;
            int k16g = (s & 3) ^ ((row >> 1) & 3);
            size_t goff = (size_t)row * rowb + k2 + k16g * 16;
            __builtin_amdgcn_global_load_lds(
                (const __attribute__((address_space(1))) void*)(Ab + goff),
                (__attribute__((address_space(3))) void*)((char*)As + s * 16), 16, 0, 0);
            __builtin_amdgcn_global_load_lds(
                (const __attribute__((address_space(1))) void*)(Bb + goff),
                (__attribute__((address_space(3))) void*)((char*)Bs + s * 16), 16, 0, 0);
        }
        __syncthreads();

        short8 a[4], b[4];
#pragma unroll
        for (int mi = 0; mi < 4; ++mi)
            a[mi] = *(const short8*)&As[(wr * 64 + mi * 16 + lrow) * 32 + kgp * 8];
#pragma unroll
        for (int ni = 0; ni < 4; ++ni)
            b[ni] = *(const short8*)&Bs[(wc * 64 + ni * 16 + lrow) * 32 + kgp * 8];
#pragma unroll
        for (int mi = 0; mi < 4; ++mi)
#pragma unroll
            for (int ni = 0; ni < 4; ++ni)
                acc[mi][ni] = __builtin_amdgcn_mfma_f32_16x16x32_bf16(a[mi], b[ni], acc[mi][ni], 0, 0, 0);
        __syncthreads();
    }

#pragma unroll
    for (int mi = 0; mi < 4; ++mi) {
#pragma unroll
        for (int ni = 0; ni < 4; ++ni) {
            int c = wc * 64 + ni * 16 + lrow;
            f32x4 v = acc[mi][ni];
#pragma unroll
            for (int j = 0; j < 4; ++j) {
                float o = v[j] + bv[ni];
                if (RELU) o = fmaxf(o, 0.f);
                Ep[(wr * 16 + kg * 4 + j) * 132 + c] = o;
            }
        }
        __syncthreads();
#pragma unroll
        for (int rr = 0; rr < 8; ++rr) {
            int rl = wv * 8 + rr;
            int grow = bm * 128 + (rl >> 4) * 64 + mi * 16 + (rl & 15);
            size_t base = (size_t)grow * N + bn * 128;
#pragma unroll
            for (int hh = 0; hh < 2; ++hh) {
                int c = hh * 64 + lane;
                C[base + c] = Ep[rl * 132 + c];
            }
        }
        if (mi < 3) __syncthreads();
    }
}

// ---------------- 128x256 bf16 GEMM, BK=32, tri-buffer, 2 blocks/CU (vocab)
// Round-13 proven structure (401.3us): lane-linear staging + granule-XOR
// source permute (slice ls^(row&3)), frag reads kg^(lrow&3), counted
// vmcnt(3) tri-buffer, bn-major XCD chunking.
// Changed this round: epilogue = 2 chunks of [64][260] (barriers 9 -> 4,
// 1KB-wide store bursts), Ep aliases all 3 LDS buffers (66.5KB <= 72KB).
__global__ __launch_bounds__(512, 4)
void gemm_bt_v(const u16* __restrict__ A, const u16* __restrict__ B,
               const float* __restrict__ bias, float* __restrict__ C,
               int M, int N, int K, int tiles_m, int tiles_n) {
    extern __shared__ char smem[];   // 3 x 24576
    float* Ep = (float*)smem;        // [64][260] f32 = 66560 B

    const int tid = threadIdx.x;
    // bijective XCD-chunked remap, bn-major (bm fastest)
    int nwg = tiles_m * tiles_n;
    int q = nwg >> 3, r = nwg & 7;
    int xcd = blockIdx.x & 7, idx = blockIdx.x >> 3;
    int wg = (xcd < r ? xcd * (q + 1) : r * (q + 1) + (xcd - r) * q) + idx;
    int bn = wg / tiles_m;
    int bm = wg % tiles_m;

    const int wv = tid >> 6;
    const int lane = tid & 63;
    const int wr = wv >> 2;        // 0..1 (M half: 64 rows)
    const int wc = wv & 3;         // 0..3 (N quarter: 64 cols)
    const int lrow = lane & 15;
    const int kg = lane >> 4;      // 0..3 (16B k-slice)
    const int kgx = kg ^ (lrow & 3);  // swizzled slot for frag reads

    f32x4 acc[4][4];
#pragma unroll
    for (int i = 0; i < 4; ++i)
#pragma unroll
        for (int j = 0; j < 4; ++j) acc[i][j] = (f32x4){0.f, 0.f, 0.f, 0.f};

    const size_t rowb = (size_t)K * 2;
    const char* Ab = (const char*)A + (size_t)(bm * 128) * rowb;
    const char* Bb = (const char*)B + (size_t)(bn * 256) * rowb;

    auto STAGE = [&](int bufi, int kk) {
        char* dA = smem + bufi * 24576;
        char* dB = dA + 8192;
        int k2 = kk << 1;
        {   // A: 512 slots, rows 0..127
            int s = tid;
            int row = s >> 2, ls = s & 3;
            int gsl = ls ^ (row & 3);
            __builtin_amdgcn_global_load_lds(
                (const __attribute__((address_space(1))) void*)(Ab + (size_t)row * rowb + k2 + gsl * 16),
                (__attribute__((address_space(3))) void*)(dA + s * 16), 16, 0, 0);
        }
#pragma unroll
        for (int j = 0; j < 2; ++j) {  // B: 1024 slots, rows 0..255
            int s = j * 512 + tid;
            int row = s >> 2, ls = s & 3;
            int gsl = ls ^ (row & 3);
            __builtin_amdgcn_global_load_lds(
                (const __attribute__((address_space(1))) void*)(Bb + (size_t)row * rowb + k2 + gsl * 16),
                (__attribute__((address_space(3))) void*)(dB + s * 16), 16, 0, 0);
        }
    };

    auto COMPUTE = [&](int bufi) {
        const char* Ah = smem + bufi * 24576;
        const char* Bh = Ah + 8192;
        short8 a[4], b[4];
#pragma unroll
        for (int mi = 0; mi < 4; ++mi) {
            int rr = wr * 64 + mi * 16 + lrow;   // rr&3 == lrow&3
            a[mi] = *(const short8*)(Ah + rr * 64 + kgx * 16);
        }
#pragma unroll
        for (int ni = 0; ni < 4; ++ni) {
            int rr = wc * 64 + ni * 16 + lrow;
            b[ni] = *(const short8*)(Bh + rr * 64 + kgx * 16);
        }
        __builtin_amdgcn_s_setprio(1);
#pragma unroll
        for (int mi = 0; mi < 4; ++mi)
#pragma unroll
            for (int ni = 0; ni < 4; ++ni)
                acc[mi][ni] = __builtin_amdgcn_mfma_f32_16x16x32_bf16(a[mi], b[ni], acc[mi][ni], 0, 0, 0);
        __builtin_amdgcn_s_setprio(0);
    };

    const int nt = K >> 5;   // 16 at K=512
    STAGE(0, 0);
    STAGE(1, 32);

    for (int t = 0; t < nt; ++t) {
        if (t < nt - 1) asm volatile("s_waitcnt vmcnt(3)" ::: "memory");
        else            asm volatile("s_waitcnt vmcnt(0)" ::: "memory");
        __builtin_amdgcn_s_barrier();
        __builtin_amdgcn_sched_barrier(0);
        if (t + 2 < nt) STAGE((t + 2) % 3, (t + 2) << 5);
        COMPUTE(t % 3);
    }

    // bias after loop (keeps K-loop VMEM FIFO = stages only)
    float bv[4];
#pragma unroll
    for (int ni = 0; ni < 4; ++ni) {
        int col = bn * 256 + wc * 64 + ni * 16 + lrow;
        bv[ni] = (col < N) ? bias[col] : 0.f;
    }
    __syncthreads();  // all frag reads done before Ep overwrites LDS

    // Epilogue: 2 chunks of 64 rows x 256 cols; chunk ch = acc of waves wr==ch.
    // row-in-chunk = mi*16 + kg*4 + j.
#pragma unroll
    for (int ch = 0; ch < 2; ++ch) {
        if (wr == ch) {
#pragma unroll
            for (int mi = 0; mi < 4; ++mi)
#pragma unroll
                for (int ni = 0; ni < 4; ++ni) {
                    int c = wc * 64 + ni * 16 + lrow;
                    f32x4 v = acc[mi][ni];
#pragma unroll
                    for (int j = 0; j < 4; ++j)
                        Ep[(mi * 16 + kg * 4 + j) * 260 + c] = v[j] + bv[ni];
                }
        }
        __syncthreads();
        // 8 waves x 8 rows; 64 lanes x 16B = full 1KB row
#pragma unroll
        for (int rr = 0; rr < 8; ++rr) {
            int rl = wv * 8 + rr;
            int grow = bm * 128 + ch * 64 + rl;
            int gc0 = bn * 256 + lane * 4;
            f32x4 v = *(const f32x4*)&Ep[rl * 260 + lane * 4];
            if (gc0 + 3 < N) {
                __builtin_nontemporal_store(v, (f32x4*)&C[(size_t)grow * N + gc0]);
            } else {
#pragma unroll
                for (int e = 0; e < 4; ++e)
                    if (gc0 + e < N)
                        __builtin_nontemporal_store(v[e], &C[(size_t)grow * N + gc0 + e]);
            }
        }
        if (ch < 1) __syncthreads();
    }
}

extern "C" void kernel_launch(void* const* d_in, const int* in_sizes, int n_in,
                              void* d_out, int out_size, void* d_ws, size_t ws_size,
                              hipStream_t stream) {
    const int* x    = (const int*)d_in[0];
    const float* emb = (const float*)d_in[1];
    const float* pos = (const float*)d_in[2];
    const float* b1 = (const float*)d_in[3];
    const float* b2 = (const float*)d_in[4];
    const float* b3 = (const float*)d_in[5];
    const float* w2 = (const float*)d_in[6];
    const float* fb2 = (const float*)d_in[7];
    const float* w3 = (const float*)d_in[8];
    const float* fb3 = (const float*)d_in[9];
    const float* wo = (const float*)d_in[10];
    const float* fbo = (const float*)d_in[11];
    float* out = (float*)d_out;

    const int V = 50257;
    const int TN = 197;                 // 256-col tiles for vocab
    const int Vpad = TN * 256;          // 50432

    static bool lds_cap_set = false;
    if (!lds_cap_set) {
        hipFuncSetAttribute((const void*)gemm_bt_v,
                            hipFuncAttributeMaxDynamicSharedMemorySize, 73728);
        lds_cap_set = true;
    }

    // workspace layout
    char* p = (char*)d_ws;
    u16* WO = (u16*)p;  p += (size_t)Vpad * 512 * 2;   // 51.6 MB
    u16* W2 = (u16*)p;  p += (size_t)512 * 512 * 2;
    u16* W3 = (u16*)p;  p += (size_t)512 * 512 * 2;
    u16* Abf = (u16*)p; p += (size_t)4096 * 512 * 2;   // bf16 activations [4096,512]
    float* Hb = (float*)p;                             // f32 activations [4096,512]

    // fused: embed+pos+leaky1 (blocks 0..63) || cvt WO/W2/W3 (blocks 64..)
    pre_kernel<<<dim3(64 + 2048), dim3(256), 0, stream>>>(
        x, emb, pos, b1, Abf,
        wo, WO, V * 512 / 4, w2, W2, 512 * 512 / 4, w3, W3, 512 * 512 / 4);

    // fc2 + relu -> Hb
    gemm_bt_128<true><<<dim3(32 * 4), dim3(256), 0, stream>>>(Abf, W2, fb2, Hb, 4096, 512, 512, 4);
    // leaky2 -> Abf
    leaky_bf16_kernel<<<dim3(256), dim3(64), 0, stream>>>(Hb, b2, Abf);
    // fc3 + relu -> Hb
    gemm_bt_128<true><<<dim3(32 * 4), dim3(256), 0, stream>>>(Abf, W3, fb3, Hb, 4096, 512, 512, 4);
    // leaky3 -> Abf
    leaky_bf16_kernel<<<dim3(256), dim3(64), 0, stream>>>(Hb, b3, Abf);
    // vocab projection -> out: 128x256, tri-buffer counted vmcnt, 2 blocks/CU
    gemm_bt_v<<<dim3(32 * TN), dim3(512), 73728, stream>>>(Abf, WO, fbo, out, 4096, V, 512, 32, TN);
}

// Round 16
// 389.571 us; speedup vs baseline: 1.0923x; 1.0289x over previous
//
#include <hip/hip_runtime.h>

typedef __attribute__((ext_vector_type(8))) short short8;
typedef __attribute__((ext_vector_type(4))) float f32x4;
typedef unsigned short u16;
typedef unsigned int u32;

#define DEVI __device__ __forceinline__

// round-to-nearest-even f32 -> bf16 bits
DEVI u16 f2bf(float f) {
    union { float f; u32 u; } v; v.f = f;
    u32 r = v.u + 0x7FFFu + ((v.u >> 16) & 1u);
    return (u16)(r >> 16);
}
DEVI float bf2f(u16 x) {
    union { u32 u; float f; } v; v.u = ((u32)x) << 16;
    return v.f;
}

// ---- fused pre-kernel: [blocks 0..63] embed+pos+leaky1; [64..] cvt3 ------
__global__ __launch_bounds__(256)
void pre_kernel(const int* __restrict__ x, const float* __restrict__ emb,
                const float* __restrict__ pos, const float* __restrict__ beta,
                u16* __restrict__ Aout,
                const float* __restrict__ wo, u16* __restrict__ WO, int nwo4,
                const float* __restrict__ w2, u16* __restrict__ W2, int nw24,
                const float* __restrict__ w3, u16* __restrict__ W3, int nw34) {
    if (blockIdx.x < 64) {
        __shared__ int xs[128];
        int gtid = blockIdx.x * 256 + threadIdx.x;
        int b = gtid >> 9;
        int h = gtid & 511;
        for (int i = threadIdx.x; i < 128; i += 256) xs[i] = x[i * 32 + b];
        __syncthreads();
        float be = beta[h];
        float mem = 0.f;
        for (int t0 = 0; t0 < 128; t0 += 8) {
            float e[8];
#pragma unroll
            for (int j = 0; j < 8; ++j)
                e[j] = emb[(size_t)xs[t0 + j] * 512 + h] + pos[(t0 + j) * 512 + h];
#pragma unroll
            for (int j = 0; j < 8; ++j) {
                mem = be * mem + e[j];
                Aout[(size_t)((t0 + j) * 32 + b) * 512 + h] = f2bf(mem);
            }
        }
    } else {
        int total = nwo4 + nw24 + nw34;
        int nb = gridDim.x - 64;
        int stride = nb * 256;
        for (int i = (blockIdx.x - 64) * 256 + threadIdx.x; i < total; i += stride) {
            const float* in; u16* out; int j = i;
            if (j < nwo4) { in = wo; out = WO; }
            else if ((j -= nwo4) < nw24) { in = w2; out = W2; }
            else { j -= nw24; in = w3; out = W3; }
            float4 v = reinterpret_cast<const float4*>(in)[j];
            ushort4 o;
            o.x = f2bf(v.x); o.y = f2bf(v.y); o.z = f2bf(v.z); o.w = f2bf(v.w);
            reinterpret_cast<ushort4*>(out)[j] = o;
        }
    }
}

// ---------------- leaky over bf16 input -> bf16 A ----------------
__global__ __launch_bounds__(64)
void leaky_bf16_kernel(const u16* __restrict__ in, const float* __restrict__ beta,
                       u16* __restrict__ Aout) {
    int gtid = blockIdx.x * 64 + threadIdx.x;
    int b = gtid >> 9;
    int h = gtid & 511;
    float be = beta[h];
    float mem = 0.f;
    for (int t0 = 0; t0 < 128; t0 += 8) {
        float v[8];
#pragma unroll
        for (int j = 0; j < 8; ++j)
            v[j] = bf2f(in[(size_t)((t0 + j) * 32 + b) * 512 + h]);
#pragma unroll
        for (int j = 0; j < 8; ++j) {
            mem = be * mem + v[j];
            Aout[(size_t)((t0 + j) * 32 + b) * 512 + h] = f2bf(mem);
        }
    }
}

// ---- 64x128 bf16 GEMM + bias + ReLU -> bf16 out (fc2/fc3) ----------------
// 256 threads = 4 waves (2 row-halves x 2 col-halves), per-wave 32x64
// (acc[2][4]). Grid = (M/64)*(N/128) = 256 blocks -> 1/CU, full GPU.
// r13-proven granule-XOR staging (lane-linear LDS dst, source slice
// ls^(row&3)) + frag reads kg^(lrow&3). Single-buffer 2-barrier core.
// Epilogue: LDS [32][132] f32 transpose, packed u32 (2xbf16) stores.
__global__ __launch_bounds__(256)
void gemm_bt_64(const u16* __restrict__ A, const u16* __restrict__ B,
                const float* __restrict__ bias, u16* __restrict__ C,
                int M, int N, int K, int tiles_n) {
    __shared__ alignas(16) char smem[32 * 132 * 4];   // 16.9 KB (Ep) >= 12 KB (A+B)
    u16* As = (u16*)smem;                 // 4 KB: 64 rows x 4 granules
    u16* Bs = (u16*)(smem + 4096);        // 8 KB: 128 rows x 4 granules
    float* Ep = (float*)smem;             // [32][132] f32

    const int tid = threadIdx.x;
    int bm = blockIdx.x / tiles_n;
    int bn = blockIdx.x % tiles_n;
    const int wv = tid >> 6;
    const int lane = tid & 63;
    const int wr = wv >> 1, wc = wv & 1;
    const int lrow = lane & 15;
    const int kg = lane >> 4;
    const int kgx = kg ^ (lrow & 3);

    f32x4 acc[2][4];
#pragma unroll
    for (int i = 0; i < 2; ++i)
#pragma unroll
        for (int j = 0; j < 4; ++j) acc[i][j] = (f32x4){0.f, 0.f, 0.f, 0.f};

    const size_t rowb = (size_t)K * 2;
    const char* Ab = (const char*)A + (size_t)(bm * 64) * rowb;
    const char* Bb = (const char*)B + (size_t)(bn * 128) * rowb;

    float bv[4];
#pragma unroll
    for (int ni = 0; ni < 4; ++ni)
        bv[ni] = bias[bn * 128 + wc * 64 + ni * 16 + lrow];

    for (int k0 = 0; k0 < K; k0 += 32) {
        int k2 = k0 << 1;
        {   // A: 256 slots (64 rows x 4), 1 load/thread
            int s = tid;
            int row = s >> 2, ls = s & 3;
            int gsl = ls ^ (row & 3);
            __builtin_amdgcn_global_load_lds(
                (const __attribute__((address_space(1))) void*)(Ab + (size_t)row * rowb + k2 + gsl * 16),
                (__attribute__((address_space(3))) void*)((char*)As + s * 16), 16, 0, 0);
        }
#pragma unroll
        for (int j = 0; j < 2; ++j) {   // B: 512 slots (128 rows x 4)
            int s = j * 256 + tid;
            int row = s >> 2, ls = s & 3;
            int gsl = ls ^ (row & 3);
            __builtin_amdgcn_global_load_lds(
                (const __attribute__((address_space(1))) void*)(Bb + (size_t)row * rowb + k2 + gsl * 16),
                (__attribute__((address_space(3))) void*)((char*)Bs + s * 16), 16, 0, 0);
        }
        __syncthreads();

        short8 a[2], b[4];
#pragma unroll
        for (int mi = 0; mi < 2; ++mi) {
            int rr = wr * 32 + mi * 16 + lrow;    // rr&3 == lrow&3
            a[mi] = *(const short8*)((const char*)As + rr * 64 + kgx * 16);
        }
#pragma unroll
        for (int ni = 0; ni < 4; ++ni) {
            int rr = wc * 64 + ni * 16 + lrow;
            b[ni] = *(const short8*)((const char*)Bs + rr * 64 + kgx * 16);
        }
#pragma unroll
        for (int mi = 0; mi < 2; ++mi)
#pragma unroll
            for (int ni = 0; ni < 4; ++ni)
                acc[mi][ni] = __builtin_amdgcn_mfma_f32_16x16x32_bf16(a[mi], b[ni], acc[mi][ni], 0, 0, 0);
        __syncthreads();
    }

    // Epilogue: 2 chunks of 32 rows x 128 cols; chunk ch = rows of waves wr==ch.
#pragma unroll
    for (int ch = 0; ch < 2; ++ch) {
        if (wr == ch) {
#pragma unroll
            for (int mi = 0; mi < 2; ++mi)
#pragma unroll
                for (int ni = 0; ni < 4; ++ni) {
                    int c = wc * 64 + ni * 16 + lrow;
                    f32x4 v = acc[mi][ni];
#pragma unroll
                    for (int j = 0; j < 4; ++j)
                        Ep[(mi * 16 + kg * 4 + j) * 132 + c] = fmaxf(v[j] + bv[ni], 0.f);
                }
        }
        __syncthreads();
        // 4 waves x 8 rows; 64 lanes x u32 (2 bf16) = 256B per row
#pragma unroll
        for (int rr = 0; rr < 8; ++rr) {
            int rl = wv * 8 + rr;
            int grow = bm * 64 + ch * 32 + rl;
            float lo = Ep[rl * 132 + lane * 2];
            float hi = Ep[rl * 132 + lane * 2 + 1];
            u32 pk = (u32)f2bf(lo) | ((u32)f2bf(hi) << 16);
            *(u32*)((char*)C + ((size_t)grow * N + bn * 128 + lane * 2) * 2) = pk;
        }
        if (ch < 1) __syncthreads();
    }
}

// ---------------- 128x256 bf16 GEMM, BK=32, tri-buffer, 2 blocks/CU (vocab)
// Round-15 proven (400.8us): lane-linear staging + granule-XOR source
// permute, frag reads kg^(lrow&3), counted vmcnt(3) tri-buffer, bn-major
// XCD chunking, 2-chunk [64][260] NT epilogue. UNCHANGED.
__global__ __launch_bounds__(512, 4)
void gemm_bt_v(const u16* __restrict__ A, const u16* __restrict__ B,
               const float* __restrict__ bias, float* __restrict__ C,
               int M, int N, int K, int tiles_m, int tiles_n) {
    extern __shared__ char smem[];   // 3 x 24576
    float* Ep = (float*)smem;        // [64][260] f32 = 66560 B

    const int tid = threadIdx.x;
    int nwg = tiles_m * tiles_n;
    int q = nwg >> 3, r = nwg & 7;
    int xcd = blockIdx.x & 7, idx = blockIdx.x >> 3;
    int wg = (xcd < r ? xcd * (q + 1) : r * (q + 1) + (xcd - r) * q) + idx;
    int bn = wg / tiles_m;
    int bm = wg % tiles_m;

    const int wv = tid >> 6;
    const int lane = tid & 63;
    const int wr = wv >> 2;
    const int wc = wv & 3;
    const int lrow = lane & 15;
    const int kg = lane >> 4;
    const int kgx = kg ^ (lrow & 3);

    f32x4 acc[4][4];
#pragma unroll
    for (int i = 0; i < 4; ++i)
#pragma unroll
        for (int j = 0; j < 4; ++j) acc[i][j] = (f32x4){0.f, 0.f, 0.f, 0.f};

    const size_t rowb = (size_t)K * 2;
    const char* Ab = (const char*)A + (size_t)(bm * 128) * rowb;
    const char* Bb = (const char*)B + (size_t)(bn * 256) * rowb;

    auto STAGE = [&](int bufi, int kk) {
        char* dA = smem + bufi * 24576;
        char* dB = dA + 8192;
        int k2 = kk << 1;
        {
            int s = tid;
            int row = s >> 2, ls = s & 3;
            int gsl = ls ^ (row & 3);
            __builtin_amdgcn_global_load_lds(
                (const __attribute__((address_space(1))) void*)(Ab + (size_t)row * rowb + k2 + gsl * 16),
                (__attribute__((address_space(3))) void*)(dA + s * 16), 16, 0, 0);
        }
#pragma unroll
        for (int j = 0; j < 2; ++j) {
            int s = j * 512 + tid;
            int row = s >> 2, ls = s & 3;
            int gsl = ls ^ (row & 3);
            __builtin_amdgcn_global_load_lds(
                (const __attribute__((address_space(1))) void*)(Bb + (size_t)row * rowb + k2 + gsl * 16),
                (__attribute__((address_space(3))) void*)(dB + s * 16), 16, 0, 0);
        }
    };

    auto COMPUTE = [&](int bufi) {
        const char* Ah = smem + bufi * 24576;
        const char* Bh = Ah + 8192;
        short8 a[4], b[4];
#pragma unroll
        for (int mi = 0; mi < 4; ++mi) {
            int rr = wr * 64 + mi * 16 + lrow;
            a[mi] = *(const short8*)(Ah + rr * 64 + kgx * 16);
        }
#pragma unroll
        for (int ni = 0; ni < 4; ++ni) {
            int rr = wc * 64 + ni * 16 + lrow;
            b[ni] = *(const short8*)(Bh + rr * 64 + kgx * 16);
        }
        __builtin_amdgcn_s_setprio(1);
#pragma unroll
        for (int mi = 0; mi < 4; ++mi)
#pragma unroll
            for (int ni = 0; ni < 4; ++ni)
                acc[mi][ni] = __builtin_amdgcn_mfma_f32_16x16x32_bf16(a[mi], b[ni], acc[mi][ni], 0, 0, 0);
        __builtin_amdgcn_s_setprio(0);
    };

    const int nt = K >> 5;
    STAGE(0, 0);
    STAGE(1, 32);

    for (int t = 0; t < nt; ++t) {
        if (t < nt - 1) asm volatile("s_waitcnt vmcnt(3)" ::: "memory");
        else            asm volatile("s_waitcnt vmcnt(0)" ::: "memory");
        __builtin_amdgcn_s_barrier();
        __builtin_amdgcn_sched_barrier(0);
        if (t + 2 < nt) STAGE((t + 2) % 3, (t + 2) << 5);
        COMPUTE(t % 3);
    }

    float bv[4];
#pragma unroll
    for (int ni = 0; ni < 4; ++ni) {
        int col = bn * 256 + wc * 64 + ni * 16 + lrow;
        bv[ni] = (col < N) ? bias[col] : 0.f;
    }
    __syncthreads();

#pragma unroll
    for (int ch = 0; ch < 2; ++ch) {
        if (wr == ch) {
#pragma unroll
            for (int mi = 0; mi < 4; ++mi)
#pragma unroll
                for (int ni = 0; ni < 4; ++ni) {
                    int c = wc * 64 + ni * 16 + lrow;
                    f32x4 v = acc[mi][ni];
#pragma unroll
                    for (int j = 0; j < 4; ++j)
                        Ep[(mi * 16 + kg * 4 + j) * 260 + c] = v[j] + bv[ni];
                }
        }
        __syncthreads();
#pragma unroll
        for (int rr = 0; rr < 8; ++rr) {
            int rl = wv * 8 + rr;
            int grow = bm * 128 + ch * 64 + rl;
            int gc0 = bn * 256 + lane * 4;
            f32x4 v = *(const f32x4*)&Ep[rl * 260 + lane * 4];
            if (gc0 + 3 < N) {
                __builtin_nontemporal_store(v, (f32x4*)&C[(size_t)grow * N + gc0]);
            } else {
#pragma unroll
                for (int e = 0; e < 4; ++e)
                    if (gc0 + e < N)
                        __builtin_nontemporal_store(v[e], &C[(size_t)grow * N + gc0 + e]);
            }
        }
        if (ch < 1) __syncthreads();
    }
}

extern "C" void kernel_launch(void* const* d_in, const int* in_sizes, int n_in,
                              void* d_out, int out_size, void* d_ws, size_t ws_size,
                              hipStream_t stream) {
    const int* x    = (const int*)d_in[0];
    const float* emb = (const float*)d_in[1];
    const float* pos = (const float*)d_in[2];
    const float* b1 = (const float*)d_in[3];
    const float* b2 = (const float*)d_in[4];
    const float* b3 = (const float*)d_in[5];
    const float* w2 = (const float*)d_in[6];
    const float* fb2 = (const float*)d_in[7];
    const float* w3 = (const float*)d_in[8];
    const float* fb3 = (const float*)d_in[9];
    const float* wo = (const float*)d_in[10];
    const float* fbo = (const float*)d_in[11];
    float* out = (float*)d_out;

    const int V = 50257;
    const int TN = 197;                 // 256-col tiles for vocab
    const int Vpad = TN * 256;          // 50432

    static bool lds_cap_set = false;
    if (!lds_cap_set) {
        hipFuncSetAttribute((const void*)gemm_bt_v,
                            hipFuncAttributeMaxDynamicSharedMemorySize, 73728);
        lds_cap_set = true;
    }

    // workspace layout
    char* p = (char*)d_ws;
    u16* WO = (u16*)p;  p += (size_t)Vpad * 512 * 2;   // 51.6 MB
    u16* W2 = (u16*)p;  p += (size_t)512 * 512 * 2;
    u16* W3 = (u16*)p;  p += (size_t)512 * 512 * 2;
    u16* Abf = (u16*)p; p += (size_t)4096 * 512 * 2;   // bf16 activations [4096,512]
    u16* Hb = (u16*)p;                                 // bf16 activations [4096,512]

    // fused: embed+pos+leaky1 (blocks 0..63) || cvt WO/W2/W3 (blocks 64..)
    pre_kernel<<<dim3(64 + 2048), dim3(256), 0, stream>>>(
        x, emb, pos, b1, Abf,
        wo, WO, V * 512 / 4, w2, W2, 512 * 512 / 4, w3, W3, 512 * 512 / 4);

    // fc2 + relu -> Hb (bf16): 64x128 tiles, 256 blocks (1/CU)
    gemm_bt_64<<<dim3(64 * 4), dim3(256), 0, stream>>>(Abf, W2, fb2, Hb, 4096, 512, 512, 4);
    // leaky2 -> Abf
    leaky_bf16_kernel<<<dim3(256), dim3(64), 0, stream>>>(Hb, b2, Abf);
    // fc3 + relu -> Hb
    gemm_bt_64<<<dim3(64 * 4), dim3(256), 0, stream>>>(Abf, W3, fb3, Hb, 4096, 512, 512, 4);
    // leaky3 -> Abf
    leaky_bf16_kernel<<<dim3(256), dim3(64), 0, stream>>>(Hb, b3, Abf);
    // vocab projection -> out: 128x256, tri-buffer counted vmcnt, 2 blocks/CU
    gemm_bt_v<<<dim3(32 * TN), dim3(512), 73728, stream>>>(Abf, WO, fbo, out, 4096, V, 512, 32, TN);
}

// Round 17
// 383.346 us; speedup vs baseline: 1.1100x; 1.0162x over previous
//
#include <hip/hip_runtime.h>

typedef __attribute__((ext_vector_type(8))) short short8;
typedef __attribute__((ext_vector_type(4))) float f32x4;
typedef unsigned short u16;
typedef unsigned int u32;

#define DEVI __device__ __forceinline__

// barrier that does NOT drain vmcnt (keeps NT stores / prefetch in flight):
// LDS ordering only (ds ops tracked by lgkmcnt)
#define LGKM_BARRIER() do {                                         \
    asm volatile("s_waitcnt lgkmcnt(0)" ::: "memory");              \
    __builtin_amdgcn_sched_barrier(0);                              \
    __builtin_amdgcn_s_barrier();                                   \
    __builtin_amdgcn_sched_barrier(0);                              \
} while (0)

// round-to-nearest-even f32 -> bf16 bits
DEVI u16 f2bf(float f) {
    union { float f; u32 u; } v; v.f = f;
    u32 r = v.u + 0x7FFFu + ((v.u >> 16) & 1u);
    return (u16)(r >> 16);
}
DEVI float bf2f(u16 x) {
    union { u32 u; float f; } v; v.u = ((u32)x) << 16;
    return v.f;
}

// ---- fused pre-kernel: [blocks 0..63] embed+pos+leaky1; [64..] cvt3 ------
__global__ __launch_bounds__(256)
void pre_kernel(const int* __restrict__ x, const float* __restrict__ emb,
                const float* __restrict__ pos, const float* __restrict__ beta,
                u16* __restrict__ Aout,
                const float* __restrict__ wo, u16* __restrict__ WO, int nwo4,
                const float* __restrict__ w2, u16* __restrict__ W2, int nw24,
                const float* __restrict__ w3, u16* __restrict__ W3, int nw34) {
    if (blockIdx.x < 64) {
        __shared__ int xs[128];
        int gtid = blockIdx.x * 256 + threadIdx.x;
        int b = gtid >> 9;
        int h = gtid & 511;
        for (int i = threadIdx.x; i < 128; i += 256) xs[i] = x[i * 32 + b];
        __syncthreads();
        float be = beta[h];
        float mem = 0.f;
        for (int t0 = 0; t0 < 128; t0 += 8) {
            float e[8];
#pragma unroll
            for (int j = 0; j < 8; ++j)
                e[j] = emb[(size_t)xs[t0 + j] * 512 + h] + pos[(t0 + j) * 512 + h];
#pragma unroll
            for (int j = 0; j < 8; ++j) {
                mem = be * mem + e[j];
                Aout[(size_t)((t0 + j) * 32 + b) * 512 + h] = f2bf(mem);
            }
        }
    } else {
        int total = nwo4 + nw24 + nw34;
        int nb = gridDim.x - 64;
        int stride = nb * 256;
        for (int i = (blockIdx.x - 64) * 256 + threadIdx.x; i < total; i += stride) {
            const float* in; u16* out; int j = i;
            if (j < nwo4) { in = wo; out = WO; }
            else if ((j -= nwo4) < nw24) { in = w2; out = W2; }
            else { j -= nw24; in = w3; out = W3; }
            float4 v = reinterpret_cast<const float4*>(in)[j];
            ushort4 o;
            o.x = f2bf(v.x); o.y = f2bf(v.y); o.z = f2bf(v.z); o.w = f2bf(v.w);
            reinterpret_cast<ushort4*>(out)[j] = o;
        }
    }
}

// ---------------- leaky over bf16 input -> bf16 A ----------------
__global__ __launch_bounds__(64)
void leaky_bf16_kernel(const u16* __restrict__ in, const float* __restrict__ beta,
                       u16* __restrict__ Aout) {
    int gtid = blockIdx.x * 64 + threadIdx.x;
    int b = gtid >> 9;
    int h = gtid & 511;
    float be = beta[h];
    float mem = 0.f;
    for (int t0 = 0; t0 < 128; t0 += 8) {
        float v[8];
#pragma unroll
        for (int j = 0; j < 8; ++j)
            v[j] = bf2f(in[(size_t)((t0 + j) * 32 + b) * 512 + h]);
#pragma unroll
        for (int j = 0; j < 8; ++j) {
            mem = be * mem + v[j];
            Aout[(size_t)((t0 + j) * 32 + b) * 512 + h] = f2bf(mem);
        }
    }
}

// ---- 64x128 bf16 GEMM + bias + ReLU -> bf16 out (fc2/fc3) ----------------
__global__ __launch_bounds__(256)
void gemm_bt_64(const u16* __restrict__ A, const u16* __restrict__ B,
                const float* __restrict__ bias, u16* __restrict__ C,
                int M, int N, int K, int tiles_n) {
    __shared__ alignas(16) char smem[32 * 132 * 4];   // 16.9 KB (Ep) >= 12 KB (A+B)
    u16* As = (u16*)smem;                 // 4 KB: 64 rows x 4 granules
    u16* Bs = (u16*)(smem + 4096);        // 8 KB: 128 rows x 4 granules
    float* Ep = (float*)smem;             // [32][132] f32

    const int tid = threadIdx.x;
    int bm = blockIdx.x / tiles_n;
    int bn = blockIdx.x % tiles_n;
    const int wv = tid >> 6;
    const int lane = tid & 63;
    const int wr = wv >> 1, wc = wv & 1;
    const int lrow = lane & 15;
    const int kg = lane >> 4;
    const int kgx = kg ^ (lrow & 3);

    f32x4 acc[2][4];
#pragma unroll
    for (int i = 0; i < 2; ++i)
#pragma unroll
        for (int j = 0; j < 4; ++j) acc[i][j] = (f32x4){0.f, 0.f, 0.f, 0.f};

    const size_t rowb = (size_t)K * 2;
    const char* Ab = (const char*)A + (size_t)(bm * 64) * rowb;
    const char* Bb = (const char*)B + (size_t)(bn * 128) * rowb;

    float bv[4];
#pragma unroll
    for (int ni = 0; ni < 4; ++ni)
        bv[ni] = bias[bn * 128 + wc * 64 + ni * 16 + lrow];

    for (int k0 = 0; k0 < K; k0 += 32) {
        int k2 = k0 << 1;
        {
            int s = tid;
            int row = s >> 2, ls = s & 3;
            int gsl = ls ^ (row & 3);
            __builtin_amdgcn_global_load_lds(
                (const __attribute__((address_space(1))) void*)(Ab + (size_t)row * rowb + k2 + gsl * 16),
                (__attribute__((address_space(3))) void*)((char*)As + s * 16), 16, 0, 0);
        }
#pragma unroll
        for (int j = 0; j < 2; ++j) {
            int s = j * 256 + tid;
            int row = s >> 2, ls = s & 3;
            int gsl = ls ^ (row & 3);
            __builtin_amdgcn_global_load_lds(
                (const __attribute__((address_space(1))) void*)(Bb + (size_t)row * rowb + k2 + gsl * 16),
                (__attribute__((address_space(3))) void*)((char*)Bs + s * 16), 16, 0, 0);
        }
        __syncthreads();

        short8 a[2], b[4];
#pragma unroll
        for (int mi = 0; mi < 2; ++mi) {
            int rr = wr * 32 + mi * 16 + lrow;
            a[mi] = *(const short8*)((const char*)As + rr * 64 + kgx * 16);
        }
#pragma unroll
        for (int ni = 0; ni < 4; ++ni) {
            int rr = wc * 64 + ni * 16 + lrow;
            b[ni] = *(const short8*)((const char*)Bs + rr * 64 + kgx * 16);
        }
#pragma unroll
        for (int mi = 0; mi < 2; ++mi)
#pragma unroll
            for (int ni = 0; ni < 4; ++ni)
                acc[mi][ni] = __builtin_amdgcn_mfma_f32_16x16x32_bf16(a[mi], b[ni], acc[mi][ni], 0, 0, 0);
        __syncthreads();
    }

#pragma unroll
    for (int ch = 0; ch < 2; ++ch) {
        if (wr == ch) {
#pragma unroll
            for (int mi = 0; mi < 2; ++mi)
#pragma unroll
                for (int ni = 0; ni < 4; ++ni) {
                    int c = wc * 64 + ni * 16 + lrow;
                    f32x4 v = acc[mi][ni];
#pragma unroll
                    for (int j = 0; j < 4; ++j)
                        Ep[(mi * 16 + kg * 4 + j) * 132 + c] = fmaxf(v[j] + bv[ni], 0.f);
                }
        }
        __syncthreads();
#pragma unroll
        for (int rr = 0; rr < 8; ++rr) {
            int rl = wv * 8 + rr;
            int grow = bm * 64 + ch * 32 + rl;
            float lo = Ep[rl * 132 + lane * 2];
            float hi = Ep[rl * 132 + lane * 2 + 1];
            u32 pk = (u32)f2bf(lo) | ((u32)f2bf(hi) << 16);
            *(u32*)((char*)C + ((size_t)grow * N + bn * 128 + lane * 2) * 2) = pk;
        }
        if (ch < 1) __syncthreads();
    }
}

// ---------------- 128x256 bf16 GEMM, BK=32, tri-buffer, 2 blocks/CU (vocab)
// r15/r16 proven core. CHANGED THIS ROUND: epilogue barriers are lgkmcnt-only
// (s_waitcnt lgkmcnt(0); s_barrier) instead of __syncthreads, which emits
// s_waitcnt vmcnt(0) and drains all in-flight NT stores per chunk. Stores now
// stay in flight across the whole epilogue and drain once at wave exit,
// overlapping the next block's prologue/K-loop on the same CU.
__global__ __launch_bounds__(512, 4)
void gemm_bt_v(const u16* __restrict__ A, const u16* __restrict__ B,
               const float* __restrict__ bias, float* __restrict__ C,
               int M, int N, int K, int tiles_m, int tiles_n) {
    extern __shared__ char smem[];   // 3 x 24576
    float* Ep = (float*)smem;        // [64][260] f32 = 66560 B

    const int tid = threadIdx.x;
    int nwg = tiles_m * tiles_n;
    int q = nwg >> 3, r = nwg & 7;
    int xcd = blockIdx.x & 7, idx = blockIdx.x >> 3;
    int wg = (xcd < r ? xcd * (q + 1) : r * (q + 1) + (xcd - r) * q) + idx;
    int bn = wg / tiles_m;
    int bm = wg % tiles_m;

    const int wv = tid >> 6;
    const int lane = tid & 63;
    const int wr = wv >> 2;
    const int wc = wv & 3;
    const int lrow = lane & 15;
    const int kg = lane >> 4;
    const int kgx = kg ^ (lrow & 3);

    f32x4 acc[4][4];
#pragma unroll
    for (int i = 0; i < 4; ++i)
#pragma unroll
        for (int j = 0; j < 4; ++j) acc[i][j] = (f32x4){0.f, 0.f, 0.f, 0.f};

    const size_t rowb = (size_t)K * 2;
    const char* Ab = (const char*)A + (size_t)(bm * 128) * rowb;
    const char* Bb = (const char*)B + (size_t)(bn * 256) * rowb;

    auto STAGE = [&](int bufi, int kk) {
        char* dA = smem + bufi * 24576;
        char* dB = dA + 8192;
        int k2 = kk << 1;
        {
            int s = tid;
            int row = s >> 2, ls = s & 3;
            int gsl = ls ^ (row & 3);
            __builtin_amdgcn_global_load_lds(
                (const __attribute__((address_space(1))) void*)(Ab + (size_t)row * rowb + k2 + gsl * 16),
                (__attribute__((address_space(3))) void*)(dA + s * 16), 16, 0, 0);
        }
#pragma unroll
        for (int j = 0; j < 2; ++j) {
            int s = j * 512 + tid;
            int row = s >> 2, ls = s & 3;
            int gsl = ls ^ (row & 3);
            __builtin_amdgcn_global_load_lds(
                (const __attribute__((address_space(1))) void*)(Bb + (size_t)row * rowb + k2 + gsl * 16),
                (__attribute__((address_space(3))) void*)(dB + s * 16), 16, 0, 0);
        }
    };

    auto COMPUTE = [&](int bufi) {
        const char* Ah = smem + bufi * 24576;
        const char* Bh = Ah + 8192;
        short8 a[4], b[4];
#pragma unroll
        for (int mi = 0; mi < 4; ++mi) {
            int rr = wr * 64 + mi * 16 + lrow;
            a[mi] = *(const short8*)(Ah + rr * 64 + kgx * 16);
        }
#pragma unroll
        for (int ni = 0; ni < 4; ++ni) {
            int rr = wc * 64 + ni * 16 + lrow;
            b[ni] = *(const short8*)(Bh + rr * 64 + kgx * 16);
        }
        __builtin_amdgcn_s_setprio(1);
#pragma unroll
        for (int mi = 0; mi < 4; ++mi)
#pragma unroll
            for (int ni = 0; ni < 4; ++ni)
                acc[mi][ni] = __builtin_amdgcn_mfma_f32_16x16x32_bf16(a[mi], b[ni], acc[mi][ni], 0, 0, 0);
        __builtin_amdgcn_s_setprio(0);
    };

    const int nt = K >> 5;
    STAGE(0, 0);
    STAGE(1, 32);

    for (int t = 0; t < nt; ++t) {
        if (t < nt - 1) asm volatile("s_waitcnt vmcnt(3)" ::: "memory");
        else            asm volatile("s_waitcnt vmcnt(0)" ::: "memory");
        __builtin_amdgcn_s_barrier();
        __builtin_amdgcn_sched_barrier(0);
        if (t + 2 < nt) STAGE((t + 2) % 3, (t + 2) << 5);
        COMPUTE(t % 3);
    }

    float bv[4];
#pragma unroll
    for (int ni = 0; ni < 4; ++ni) {
        int col = bn * 256 + wc * 64 + ni * 16 + lrow;
        bv[ni] = (col < N) ? bias[col] : 0.f;
    }
    // all frag ds_reads done before Ep overwrite (lgkm only; stage loads
    // already drained by the t = nt-1 vmcnt(0))
    LGKM_BARRIER();

    // Epilogue: 2 chunks of 64 rows x 256 cols; NT stores never drained here.
#pragma unroll
    for (int ch = 0; ch < 2; ++ch) {
        if (wr == ch) {
#pragma unroll
            for (int mi = 0; mi < 4; ++mi)
#pragma unroll
                for (int ni = 0; ni < 4; ++ni) {
                    int c = wc * 64 + ni * 16 + lrow;
                    f32x4 v = acc[mi][ni];
#pragma unroll
                    for (int j = 0; j < 4; ++j)
                        Ep[(mi * 16 + kg * 4 + j) * 260 + c] = v[j] + bv[ni];
                }
        }
        LGKM_BARRIER();
#pragma unroll
        for (int rr = 0; rr < 8; ++rr) {
            int rl = wv * 8 + rr;
            int grow = bm * 128 + ch * 64 + rl;
            int gc0 = bn * 256 + lane * 4;
            f32x4 v = *(const f32x4*)&Ep[rl * 260 + lane * 4];
            if (gc0 + 3 < N) {
                __builtin_nontemporal_store(v, (f32x4*)&C[(size_t)grow * N + gc0]);
            } else {
#pragma unroll
                for (int e = 0; e < 4; ++e)
                    if (gc0 + e < N)
                        __builtin_nontemporal_store(v[e], &C[(size_t)grow * N + gc0 + e]);
            }
        }
        if (ch < 1) LGKM_BARRIER();
    }
}

extern "C" void kernel_launch(void* const* d_in, const int* in_sizes, int n_in,
                              void* d_out, int out_size, void* d_ws, size_t ws_size,
                              hipStream_t stream) {
    const int* x    = (const int*)d_in[0];
    const float* emb = (const float*)d_in[1];
    const float* pos = (const float*)d_in[2];
    const float* b1 = (const float*)d_in[3];
    const float* b2 = (const float*)d_in[4];
    const float* b3 = (const float*)d_in[5];
    const float* w2 = (const float*)d_in[6];
    const float* fb2 = (const float*)d_in[7];
    const float* w3 = (const float*)d_in[8];
    const float* fb3 = (const float*)d_in[9];
    const float* wo = (const float*)d_in[10];
    const float* fbo = (const float*)d_in[11];
    float* out = (float*)d_out;

    const int V = 50257;
    const int TN = 197;                 // 256-col tiles for vocab
    const int Vpad = TN * 256;          // 50432

    static bool lds_cap_set = false;
    if (!lds_cap_set) {
        hipFuncSetAttribute((const void*)gemm_bt_v,
                            hipFuncAttributeMaxDynamicSharedMemorySize, 73728);
        lds_cap_set = true;
    }

    // workspace layout
    char* p = (char*)d_ws;
    u16* WO = (u16*)p;  p += (size_t)Vpad * 512 * 2;   // 51.6 MB
    u16* W2 = (u16*)p;  p += (size_t)512 * 512 * 2;
    u16* W3 = (u16*)p;  p += (size_t)512 * 512 * 2;
    u16* Abf = (u16*)p; p += (size_t)4096 * 512 * 2;   // bf16 activations [4096,512]
    u16* Hb = (u16*)p;                                 // bf16 activations [4096,512]

    // fused: embed+pos+leaky1 (blocks 0..63) || cvt WO/W2/W3 (blocks 64..)
    pre_kernel<<<dim3(64 + 2048), dim3(256), 0, stream>>>(
        x, emb, pos, b1, Abf,
        wo, WO, V * 512 / 4, w2, W2, 512 * 512 / 4, w3, W3, 512 * 512 / 4);

    // fc2 + relu -> Hb (bf16): 64x128 tiles, 256 blocks (1/CU)
    gemm_bt_64<<<dim3(64 * 4), dim3(256), 0, stream>>>(Abf, W2, fb2, Hb, 4096, 512, 512, 4);
    // leaky2 -> Abf
    leaky_bf16_kernel<<<dim3(256), dim3(64), 0, stream>>>(Hb, b2, Abf);
    // fc3 + relu -> Hb
    gemm_bt_64<<<dim3(64 * 4), dim3(256), 0, stream>>>(Abf, W3, fb3, Hb, 4096, 512, 512, 4);
    // leaky3 -> Abf
    leaky_bf16_kernel<<<dim3(256), dim3(64), 0, stream>>>(Hb, b3, Abf);
    // vocab projection -> out: 128x256, tri-buffer counted vmcnt, 2 blocks/CU
    gemm_bt_v<<<dim3(32 * TN), dim3(512), 73728, stream>>>(Abf, WO, fbo, out, 4096, V, 512, 32, TN);
}